// Round 1
// 119.907 us; speedup vs baseline: 1.0324x; 1.0324x over previous
//
#include <hip/hip_runtime.h>
#include <stdint.h>

#define NB 4
#define NC 17
#define HH 8
#define SS 512
#define DD 64
#define CT 64   // columns per block tile

typedef __attribute__((ext_vector_type(8))) short bf16x8;
typedef __attribute__((ext_vector_type(4))) float f32x4;

// ws layout (bytes):
//   W1mbf : [17][8][64][64] bf16 = 1,114,112
//   ridx  : [8][512] int (rows grouped by bucket bi)
//   gst   : [8][6] int group offsets
#define WS_W1   0
#define WS_RIDX 1114112
#define WS_GST  (WS_RIDX + 16384)

__device__ __forceinline__ unsigned short f2bf(float f) {
  unsigned int x; __builtin_memcpy(&x, &f, 4);
  return (unsigned short)((x + 0x7fff + ((x >> 16) & 1)) >> 16);
}
__device__ __forceinline__ bf16x8 cvt8(float4 a, float4 b) {
  union { bf16x8 v; unsigned short u[8]; } t;
  t.u[0] = f2bf(a.x); t.u[1] = f2bf(a.y); t.u[2] = f2bf(a.z); t.u[3] = f2bf(a.w);
  t.u[4] = f2bf(b.x); t.u[5] = f2bf(b.y); t.u[6] = f2bf(b.z); t.u[7] = f2bf(b.w);
  return t.v;
}

// ---- K0: blocks 0..7: per-b counting sort of rows by bucket bi.
//          blocks 8..143: W1mbf[c][h][.] = sum_B W1[B][h][.]*softmax(alpha)[c,B,h]
__global__ __launch_bounds__(256) void k_prep(const int* __restrict__ bseq,
                                              const float* __restrict__ W1,
                                              const float* __restrict__ alpha,
                                              int* __restrict__ ridx,
                                              int* __restrict__ gst,
                                              unsigned short* __restrict__ W1mbf) {
  int tid = threadIdx.x;
  if (blockIdx.x < 8) {
    int b = blockIdx.x;
    __shared__ int cnt[5], base[6], cur[5];
    if (tid < 5) cnt[tid] = 0;
    __syncthreads();
    for (int j = tid; j < SS; j += blockDim.x) atomicAdd(&cnt[bseq[b * SS + j]], 1);
    __syncthreads();
    if (tid == 0) {
      base[0] = 0;
      for (int k = 0; k < 5; k++) base[k + 1] = base[k] + cnt[k];
      for (int k = 0; k < 6; k++) gst[b * 6 + k] = base[k];
    }
    __syncthreads();
    if (tid < 5) cur[tid] = base[tid];
    __syncthreads();
    for (int j = tid; j < SS; j += blockDim.x) {
      int p = atomicAdd(&cur[bseq[b * SS + j]], 1);
      ridx[b * SS + p] = j;
    }
  } else {
    int cb = blockIdx.x - 8;
    int c = cb >> 3, hh = cb & 7;
    __shared__ float sm[NB];
    if (tid == 0) {
      float a[NB], mx = -1e30f;
      for (int B = 0; B < NB; B++) { a[B] = alpha[(c * NB + B) * HH + hh]; mx = fmaxf(mx, a[B]); }
      float s = 0.f;
      for (int B = 0; B < NB; B++) { a[B] = __expf(a[B] - mx); s += a[B]; }
      for (int B = 0; B < NB; B++) sm[B] = a[B] / s;
    }
    __syncthreads();
    float s0 = sm[0], s1 = sm[1], s2 = sm[2], s3 = sm[3];
    const float* w0p = &W1[((0 * HH + hh) << 12)];
    const float* w1p = &W1[((1 * HH + hh) << 12)];
    const float* w2p = &W1[((2 * HH + hh) << 12)];
    const float* w3p = &W1[((3 * HH + hh) << 12)];
    unsigned short* dst = &W1mbf[((size_t)(c * HH + hh)) << 12];
    for (int idx = tid * 4; idx < DD * DD; idx += 1024) {
      float4 w0 = *(const float4*)(w0p + idx);
      float4 w1 = *(const float4*)(w1p + idx);
      float4 w2 = *(const float4*)(w2p + idx);
      float4 w3 = *(const float4*)(w3p + idx);
      union { unsigned short u[4]; uint2 v; } o;
      o.u[0] = f2bf(w0.x * s0 + w1.x * s1 + w2.x * s2 + w3.x * s3);
      o.u[1] = f2bf(w0.y * s0 + w1.y * s1 + w2.y * s2 + w3.y * s3);
      o.u[2] = f2bf(w0.z * s0 + w1.z * s1 + w2.z * s2 + w3.z * s3);
      o.u[3] = f2bf(w0.w * s0 + w1.w * s1 + w2.w * s2 + w3.w * s3);
      *(uint2*)(dst + idx) = o.v;
    }
  }
}

// ---- Fused: block = (bh, 64-col tile). 12 waves (768 thr) -> 2 blocks/CU = 24 waves/CU.
// Phase 1 builds T[5][64][.] in LDS, phase 2 does the scores GEMM with 2-way row-tile ILP.
__global__ __launch_bounds__(768, 6) void k_fused(const float* __restrict__ query,
                                                  const float* __restrict__ key,
                                                  const int* __restrict__ bseq,
                                                  const unsigned short* __restrict__ W1mbf,
                                                  const int* __restrict__ ridx,
                                                  const int* __restrict__ gst,
                                                  float* __restrict__ out) {
  int bx = blockIdx.x;
  int bh = bx & 63, jt = bx >> 6;   // same-bh blocks 64 apart -> same XCD
  int b = bh >> 3, h = bh & 7;
  int j0 = jt * CT;
  int tid = threadIdx.x, wave = tid >> 6, lane = tid & 63;
  int quad = lane >> 4, l16 = lane & 15;

  __shared__ __align__(16) unsigned short Tl[5][CT][72];  // 46,080 B
  __shared__ int ord[CT];
  __shared__ int ridxs[SS];            // ridx[b][.] staged to LDS (kills gather chain)
  __shared__ int p1list[40], p2list[40];
  __shared__ int n1tot, n2tot;

  // stage ridx for this b (coalesced, once)
  if (tid < SS) ridxs[tid] = ridx[b * SS + tid];

  // ---- wave-0 ballot-based setup: column grouping + work lists, 1 barrier total ----
  if (wave == 0) {
    int mybj = bseq[b * SS + j0 + lane];     // 64 lanes = 64 columns
    unsigned long long mm[5];
    int pb[6];
    pb[0] = 0;
#pragma unroll
    for (int a = 0; a < 5; a++) {
      mm[a] = __ballot(mybj == a);
      pb[a + 1] = pb[a] + (int)__popcll(mm[a]);
    }
    int pos = pb[mybj] + (int)__popcll(mm[mybj] & ((1ull << lane) - 1ull));
    ord[pos] = lane;

    int n1b_[5]; int t = 0;
#pragma unroll
    for (int a = 0; a < 5; a++) {
      n1b_[a] = t;
      t += ((pb[a + 1] - pb[a] + 15) >> 4) * ((a == 0) ? 1 : 5);
    }
    if (lane == 0) n1tot = t;

    if (lane < 5) {
      int a = lane;
      int ls = pb[a], le = pb[a + 1];
      int w = n1b_[a];
      for (int t0 = ls; t0 < le; t0 += 16) {
        if (a == 0) {
          p1list[w++] = t0 | (le << 6) | (1 << 21);  // c=0, bcast all planes
        } else {
#pragma unroll
          for (int B = 0; B < 5; B++) {
            int c = (B == 0) ? 0 : (B - 1) * NB + a;
            p1list[w++] = t0 | (le << 6) | (c << 13) | (B << 18);
          }
        }
      }
      int g[6];
#pragma unroll
      for (int k = 0; k < 6; k++) g[k] = gst[b * 6 + k];
      int w2 = 0;
      for (int aa = 0; aa < a; aa++) w2 += (g[aa + 1] - g[aa] + 15) >> 4;
      int gs = g[a], ge = g[a + 1];
      for (int p0 = gs; p0 < ge; p0 += 16)
        p2list[w2++] = p0 | (ge << 10) | (a << 20);
      if (a == 4) n2tot = w2;
    }
  }
  __syncthreads();

  // ---- phase 1: Tl[B][col][m] = sum_n key[col][n] * W_c(B,bj)[m][n] ----
  for (int idx = wave; idx < n1tot; idx += 12) {
    int e = p1list[idx];
    int t0 = e & 63, le = (e >> 6) & 127, c = (e >> 13) & 31, B = (e >> 18) & 7;
    int bc = (e >> 21) & 1;
    const unsigned short* Wc = W1mbf + ((size_t)(c * HH + h) << 12);
    int p = t0 + l16; if (p > le - 1) p = le - 1;
    int cl = ord[p];
    const float* kp = &key[((size_t)(bh * SS + j0 + cl)) * DD + quad * 8];
    float4 ka = *(const float4*)kp, kb = *(const float4*)(kp + 4);
    float4 kc = *(const float4*)(kp + 32), kd = *(const float4*)(kp + 36);
    bf16x8 af0 = cvt8(ka, kb);
    bf16x8 af1 = cvt8(kc, kd);
    int cr[4];
#pragma unroll
    for (int reg = 0; reg < 4; reg++) {
      int pr = t0 + quad * 4 + reg;
      cr[reg] = (pr < le) ? ord[pr] : -1;
    }
#pragma unroll
    for (int nt = 0; nt < 4; nt++) {
      const unsigned short* wp = &Wc[(nt * 16 + l16) * DD + quad * 8];
      bf16x8 b0 = *(const bf16x8*)wp;
      bf16x8 b1 = *(const bf16x8*)(wp + 32);
      f32x4 acc = {0.f, 0.f, 0.f, 0.f};
      __builtin_amdgcn_s_setprio(1);
      acc = __builtin_amdgcn_mfma_f32_16x16x32_bf16(af0, b0, acc, 0, 0, 0);
      acc = __builtin_amdgcn_mfma_f32_16x16x32_bf16(af1, b1, acc, 0, 0, 0);
      __builtin_amdgcn_s_setprio(0);
#pragma unroll
      for (int reg = 0; reg < 4; reg++) {
        if (cr[reg] >= 0) {
          unsigned short v = f2bf(acc[reg]);
          if (bc) {
#pragma unroll
            for (int Bw = 0; Bw < 5; Bw++) Tl[Bw][cr[reg]][nt * 16 + l16] = v;
          } else {
            Tl[B][cr[reg]][nt * 16 + l16] = v;
          }
        }
      }
    }
  }
  __syncthreads();

  // ---- phase 2: out[r][j0..j0+63] = q[r,:] dot Tl[bi(r)][col][:], 2-way ILP ----
  for (int i0 = wave * 2; i0 < n2tot; i0 += 24) {
    int e0 = p2list[i0];
    bool has1 = (i0 + 1) < n2tot;
    int e1 = has1 ? p2list[i0 + 1] : e0;

    int p0a = e0 & 1023, gea = (e0 >> 10) & 1023, Ba = e0 >> 20;
    int p0b = e1 & 1023, geb = (e1 >> 10) & 1023, Bb = e1 >> 20;

    // sequential a-then-b convert: lower peak VGPR liveness for the 85-reg cap
    int pa = p0a + l16; if (pa > gea - 1) pa = gea - 1;
    int ra = ridxs[pa];
    const float* qa = &query[((size_t)(bh * SS + ra)) * DD + quad * 8];
    float4 a0 = *(const float4*)qa, a1 = *(const float4*)(qa + 4);
    float4 a2 = *(const float4*)(qa + 32), a3 = *(const float4*)(qa + 36);
    bf16x8 afa0 = cvt8(a0, a1), afa1 = cvt8(a2, a3);

    int pb_ = p0b + l16; if (pb_ > geb - 1) pb_ = geb - 1;
    int rb = ridxs[pb_];
    const float* qb = &query[((size_t)(bh * SS + rb)) * DD + quad * 8];
    float4 b0_ = *(const float4*)qb, b1_ = *(const float4*)(qb + 4);
    float4 b2_ = *(const float4*)(qb + 32), b3_ = *(const float4*)(qb + 36);
    bf16x8 afb0 = cvt8(b0_, b1_), afb1 = cvt8(b2_, b3_);

    int rra[4], rrb[4];
#pragma unroll
    for (int reg = 0; reg < 4; reg++) {
      int pra = p0a + quad * 4 + reg;
      rra[reg] = (pra < gea) ? ridxs[pra] : -1;
      int prb = p0b + quad * 4 + reg;
      rrb[reg] = (has1 && prb < geb) ? ridxs[prb] : -1;
    }
#pragma unroll
    for (int ct = 0; ct < CT / 16; ct++) {
      const unsigned short* tpa = &Tl[Ba][ct * 16 + l16][quad * 8];
      const unsigned short* tpb = &Tl[Bb][ct * 16 + l16][quad * 8];
      bf16x8 ba0 = *(const bf16x8*)tpa;
      bf16x8 ba1 = *(const bf16x8*)(tpa + 32);
      bf16x8 bb0 = *(const bf16x8*)tpb;
      bf16x8 bb1 = *(const bf16x8*)(tpb + 32);
      f32x4 acca = {0.f, 0.f, 0.f, 0.f}, accb = {0.f, 0.f, 0.f, 0.f};
      __builtin_amdgcn_s_setprio(1);
      acca = __builtin_amdgcn_mfma_f32_16x16x32_bf16(afa0, ba0, acca, 0, 0, 0);
      accb = __builtin_amdgcn_mfma_f32_16x16x32_bf16(afb0, bb0, accb, 0, 0, 0);
      acca = __builtin_amdgcn_mfma_f32_16x16x32_bf16(afa1, ba1, acca, 0, 0, 0);
      accb = __builtin_amdgcn_mfma_f32_16x16x32_bf16(afb1, bb1, accb, 0, 0, 0);
      __builtin_amdgcn_s_setprio(0);
#pragma unroll
      for (int reg = 0; reg < 4; reg++) {
        if (rra[reg] >= 0)
          __builtin_nontemporal_store(acca[reg],
              &out[((size_t)(bh * SS + rra[reg])) * SS + j0 + ct * 16 + l16]);
        if (rrb[reg] >= 0)
          __builtin_nontemporal_store(accb[reg],
              &out[((size_t)(bh * SS + rrb[reg])) * SS + j0 + ct * 16 + l16]);
      }
    }
  }
}

extern "C" void kernel_launch(void* const* d_in, const int* in_sizes, int n_in,
                              void* d_out, int out_size, void* d_ws, size_t ws_size,
                              hipStream_t stream) {
  const float* q = (const float*)d_in[0];
  const float* k = (const float*)d_in[1];
  const int* bseq = (const int*)d_in[2];
  const float* W1 = (const float*)d_in[3];
  const float* alpha = (const float*)d_in[4];
  float* out = (float*)d_out;
  char* ws = (char*)d_ws;
  unsigned short* W1mbf = (unsigned short*)(ws + WS_W1);
  int* ridx = (int*)(ws + WS_RIDX);
  int* gst = (int*)(ws + WS_GST);

  hipLaunchKernelGGL(k_prep, dim3(8 + NC * HH), dim3(256), 0, stream,
                     bseq, W1, alpha, ridx, gst, W1mbf);
  hipLaunchKernelGGL(k_fused, dim3(64 * (SS / CT)), dim3(768), 0, stream,
                     q, k, bseq, W1mbf, ridx, gst, out);
}

// Round 2
// 115.273 us; speedup vs baseline: 1.0739x; 1.0402x over previous
//
#include <hip/hip_runtime.h>
#include <stdint.h>

#define NB 4
#define NC 17
#define HH 8
#define SS 512
#define DD 64
#define CT 64   // columns per block tile

typedef __attribute__((ext_vector_type(8))) short bf16x8;
typedef __attribute__((ext_vector_type(4))) float f32x4;

// ws layout (bytes):
//   W1mbf : [17][8][64][64] bf16 = 1,114,112
//   ridx  : [8][512] int (rows grouped by bucket bi)
//   gst   : [8][6] int group offsets
#define WS_W1   0
#define WS_RIDX 1114112
#define WS_GST  (WS_RIDX + 16384)

__device__ __forceinline__ unsigned short f2bf(float f) {
  unsigned int x; __builtin_memcpy(&x, &f, 4);
  return (unsigned short)((x + 0x7fff + ((x >> 16) & 1)) >> 16);
}
__device__ __forceinline__ bf16x8 cvt8(float4 a, float4 b) {
  union { bf16x8 v; unsigned short u[8]; } t;
  t.u[0] = f2bf(a.x); t.u[1] = f2bf(a.y); t.u[2] = f2bf(a.z); t.u[3] = f2bf(a.w);
  t.u[4] = f2bf(b.x); t.u[5] = f2bf(b.y); t.u[6] = f2bf(b.z); t.u[7] = f2bf(b.w);
  return t.v;
}

// ---- K0: blocks 0..7: per-b counting sort of rows by bucket bi.
//          blocks 8..143: W1mbf[c][h][.] = sum_B W1[B][h][.]*softmax(alpha)[c,B,h]
__global__ __launch_bounds__(256) void k_prep(const int* __restrict__ bseq,
                                              const float* __restrict__ W1,
                                              const float* __restrict__ alpha,
                                              int* __restrict__ ridx,
                                              int* __restrict__ gst,
                                              unsigned short* __restrict__ W1mbf) {
  int tid = threadIdx.x;
  if (blockIdx.x < 8) {
    int b = blockIdx.x;
    __shared__ int cnt[5], base[6], cur[5];
    if (tid < 5) cnt[tid] = 0;
    __syncthreads();
    for (int j = tid; j < SS; j += blockDim.x) atomicAdd(&cnt[bseq[b * SS + j]], 1);
    __syncthreads();
    if (tid == 0) {
      base[0] = 0;
      for (int k = 0; k < 5; k++) base[k + 1] = base[k] + cnt[k];
      for (int k = 0; k < 6; k++) gst[b * 6 + k] = base[k];
    }
    __syncthreads();
    if (tid < 5) cur[tid] = base[tid];
    __syncthreads();
    for (int j = tid; j < SS; j += blockDim.x) {
      int p = atomicAdd(&cur[bseq[b * SS + j]], 1);
      ridx[b * SS + p] = j;
    }
  } else {
    int cb = blockIdx.x - 8;
    int c = cb >> 3, hh = cb & 7;
    __shared__ float sm[NB];
    if (tid == 0) {
      float a[NB], mx = -1e30f;
      for (int B = 0; B < NB; B++) { a[B] = alpha[(c * NB + B) * HH + hh]; mx = fmaxf(mx, a[B]); }
      float s = 0.f;
      for (int B = 0; B < NB; B++) { a[B] = __expf(a[B] - mx); s += a[B]; }
      for (int B = 0; B < NB; B++) sm[B] = a[B] / s;
    }
    __syncthreads();
    float s0 = sm[0], s1 = sm[1], s2 = sm[2], s3 = sm[3];
    const float* w0p = &W1[((0 * HH + hh) << 12)];
    const float* w1p = &W1[((1 * HH + hh) << 12)];
    const float* w2p = &W1[((2 * HH + hh) << 12)];
    const float* w3p = &W1[((3 * HH + hh) << 12)];
    unsigned short* dst = &W1mbf[((size_t)(c * HH + hh)) << 12];
    for (int idx = tid * 4; idx < DD * DD; idx += 1024) {
      float4 w0 = *(const float4*)(w0p + idx);
      float4 w1 = *(const float4*)(w1p + idx);
      float4 w2 = *(const float4*)(w2p + idx);
      float4 w3 = *(const float4*)(w3p + idx);
      union { unsigned short u[4]; uint2 v; } o;
      o.u[0] = f2bf(w0.x * s0 + w1.x * s1 + w2.x * s2 + w3.x * s3);
      o.u[1] = f2bf(w0.y * s0 + w1.y * s1 + w2.y * s2 + w3.y * s3);
      o.u[2] = f2bf(w0.z * s0 + w1.z * s1 + w2.z * s2 + w3.z * s3);
      o.u[3] = f2bf(w0.w * s0 + w1.w * s1 + w2.w * s2 + w3.w * s3);
      *(uint2*)(dst + idx) = o.v;
    }
  }
}

// ---- Fused: block = (bh, 64-col tile). 12 waves (768 thr) -> 2 blocks/CU.
// Phase 1 builds T[5][64][.] in LDS, phase 2 does the scores GEMM.
// B-fragment columns are PERMUTED (col-slot l16 <- logical col l16*4+ct) so each
// lane ends up with 4 consecutive output columns -> full-row 256B dwordx4 stores.
__global__ __launch_bounds__(768, 6) void k_fused(const float* __restrict__ query,
                                                  const float* __restrict__ key,
                                                  const int* __restrict__ bseq,
                                                  const unsigned short* __restrict__ W1mbf,
                                                  const int* __restrict__ ridx,
                                                  const int* __restrict__ gst,
                                                  float* __restrict__ out) {
  int bx = blockIdx.x;
  int bh = bx & 63, jt = bx >> 6;   // same-bh blocks 64 apart -> same XCD
  int b = bh >> 3, h = bh & 7;
  int j0 = jt * CT;
  int tid = threadIdx.x, wave = tid >> 6, lane = tid & 63;
  int quad = lane >> 4, l16 = lane & 15;

  __shared__ __align__(16) unsigned short Tl[5][CT][72];  // 46,080 B
  __shared__ int ord[CT];
  __shared__ int ridxs[SS];            // ridx[b][.] staged to LDS
  __shared__ int p1list[40], p2list[40];
  __shared__ int n1tot, n2tot;

  // stage ridx for this b (coalesced, once)
  if (tid < SS) ridxs[tid] = ridx[b * SS + tid];

  // ---- wave-0 ballot-based setup: column grouping + work lists, 1 barrier total ----
  if (wave == 0) {
    int mybj = bseq[b * SS + j0 + lane];     // 64 lanes = 64 columns
    unsigned long long mm[5];
    int pb[6];
    pb[0] = 0;
#pragma unroll
    for (int a = 0; a < 5; a++) {
      mm[a] = __ballot(mybj == a);
      pb[a + 1] = pb[a] + (int)__popcll(mm[a]);
    }
    int pos = pb[mybj] + (int)__popcll(mm[mybj] & ((1ull << lane) - 1ull));
    ord[pos] = lane;

    int n1b_[5]; int t = 0;
#pragma unroll
    for (int a = 0; a < 5; a++) {
      n1b_[a] = t;
      t += ((pb[a + 1] - pb[a] + 15) >> 4) * ((a == 0) ? 1 : 5);
    }
    if (lane == 0) n1tot = t;

    if (lane < 5) {
      int a = lane;
      int ls = pb[a], le = pb[a + 1];
      int w = n1b_[a];
      for (int t0 = ls; t0 < le; t0 += 16) {
        if (a == 0) {
          p1list[w++] = t0 | (le << 6) | (1 << 21);  // c=0, bcast all planes
        } else {
#pragma unroll
          for (int B = 0; B < 5; B++) {
            int c = (B == 0) ? 0 : (B - 1) * NB + a;
            p1list[w++] = t0 | (le << 6) | (c << 13) | (B << 18);
          }
        }
      }
      int g[6];
#pragma unroll
      for (int k = 0; k < 6; k++) g[k] = gst[b * 6 + k];
      int w2 = 0;
      for (int aa = 0; aa < a; aa++) w2 += (g[aa + 1] - g[aa] + 15) >> 4;
      int gs = g[a], ge = g[a + 1];
      for (int p0 = gs; p0 < ge; p0 += 16)
        p2list[w2++] = p0 | (ge << 10) | (a << 20);
      if (a == 4) n2tot = w2;
    }
  }
  __syncthreads();

  // ---- phase 1: Tl[B][col][m] = sum_n key[col][n] * W_c(B,bj)[m][n] ----
  // W rows loaded permuted (B col-slot l16 <- m = l16*4+nt) so each lane holds
  // 4 consecutive m's of its key-col -> packed 8B LDS writes.
  for (int idx = wave; idx < n1tot; idx += 12) {
    int e = p1list[idx];
    int t0 = e & 63, le = (e >> 6) & 127, c = (e >> 13) & 31, B = (e >> 18) & 7;
    int bc = (e >> 21) & 1;
    const unsigned short* Wc = W1mbf + ((size_t)(c * HH + h) << 12);
    int p = t0 + l16; if (p > le - 1) p = le - 1;
    int cl = ord[p];
    const float* kp = &key[((size_t)(bh * SS + j0 + cl)) * DD + quad * 8];
    float4 ka = *(const float4*)kp, kb = *(const float4*)(kp + 4);
    float4 kc = *(const float4*)(kp + 32), kd = *(const float4*)(kp + 36);
    bf16x8 af0 = cvt8(ka, kb);
    bf16x8 af1 = cvt8(kc, kd);
    int cr[4];
#pragma unroll
    for (int reg = 0; reg < 4; reg++) {
      int pr = t0 + quad * 4 + reg;
      cr[reg] = (pr < le) ? ord[pr] : -1;
    }
    f32x4 acc[4];
#pragma unroll
    for (int nt = 0; nt < 4; nt++) {
      const unsigned short* wp = &Wc[(l16 * 4 + nt) * DD + quad * 8];
      bf16x8 b0 = *(const bf16x8*)wp;
      bf16x8 b1 = *(const bf16x8*)(wp + 32);
      f32x4 z = {0.f, 0.f, 0.f, 0.f};
      __builtin_amdgcn_s_setprio(1);
      z = __builtin_amdgcn_mfma_f32_16x16x32_bf16(af0, b0, z, 0, 0, 0);
      z = __builtin_amdgcn_mfma_f32_16x16x32_bf16(af1, b1, z, 0, 0, 0);
      __builtin_amdgcn_s_setprio(0);
      acc[nt] = z;
    }
#pragma unroll
    for (int reg = 0; reg < 4; reg++) {
      if (cr[reg] >= 0) {
        union { unsigned short u[4]; uint2 v; } o;
        o.u[0] = f2bf(acc[0][reg]); o.u[1] = f2bf(acc[1][reg]);
        o.u[2] = f2bf(acc[2][reg]); o.u[3] = f2bf(acc[3][reg]);
        if (bc) {
#pragma unroll
          for (int Bw = 0; Bw < 5; Bw++) *(uint2*)&Tl[Bw][cr[reg]][l16 * 4] = o.v;
        } else {
          *(uint2*)&Tl[B][cr[reg]][l16 * 4] = o.v;
        }
      }
    }
  }
  __syncthreads();

  // ---- phase 2: out[r][j0..j0+63] = q[r,:] dot Tl[bi(r)][col][:], 2-way ILP ----
  // Tl cols loaded permuted (col-slot l16 <- col l16*4+ct): after 4 cts each lane
  // holds cols l16*4..l16*4+3 of its row -> one 16B store per row-quad, 256B/row.
  for (int i0 = wave * 2; i0 < n2tot; i0 += 24) {
    int e0 = p2list[i0];
    bool has1 = (i0 + 1) < n2tot;
    int e1 = has1 ? p2list[i0 + 1] : e0;

    int p0a = e0 & 1023, gea = (e0 >> 10) & 1023, Ba = e0 >> 20;
    int p0b = e1 & 1023, geb = (e1 >> 10) & 1023, Bb = e1 >> 20;

    int pa = p0a + l16; if (pa > gea - 1) pa = gea - 1;
    int ra = ridxs[pa];
    const float* qa = &query[((size_t)(bh * SS + ra)) * DD + quad * 8];
    float4 a0 = *(const float4*)qa, a1 = *(const float4*)(qa + 4);
    float4 a2 = *(const float4*)(qa + 32), a3 = *(const float4*)(qa + 36);
    bf16x8 afa0 = cvt8(a0, a1), afa1 = cvt8(a2, a3);

    int pb_ = p0b + l16; if (pb_ > geb - 1) pb_ = geb - 1;
    int rb = ridxs[pb_];
    const float* qb = &query[((size_t)(bh * SS + rb)) * DD + quad * 8];
    float4 b0_ = *(const float4*)qb, b1_ = *(const float4*)(qb + 4);
    float4 b2_ = *(const float4*)(qb + 32), b3_ = *(const float4*)(qb + 36);
    bf16x8 afb0 = cvt8(b0_, b1_), afb1 = cvt8(b2_, b3_);

    int rra[4], rrb[4];
#pragma unroll
    for (int reg = 0; reg < 4; reg++) {
      int pra = p0a + quad * 4 + reg;
      rra[reg] = (pra < gea) ? ridxs[pra] : -1;
      int prb = p0b + quad * 4 + reg;
      rrb[reg] = (has1 && prb < geb) ? ridxs[prb] : -1;
    }

    f32x4 acca[4], accb[4];
#pragma unroll
    for (int ct = 0; ct < 4; ct++) {
      const unsigned short* tpa = &Tl[Ba][l16 * 4 + ct][quad * 8];
      const unsigned short* tpb = &Tl[Bb][l16 * 4 + ct][quad * 8];
      bf16x8 ba0 = *(const bf16x8*)tpa;
      bf16x8 ba1 = *(const bf16x8*)(tpa + 32);
      bf16x8 bb0 = *(const bf16x8*)tpb;
      bf16x8 bb1 = *(const bf16x8*)(tpb + 32);
      f32x4 za = {0.f, 0.f, 0.f, 0.f}, zb = {0.f, 0.f, 0.f, 0.f};
      __builtin_amdgcn_s_setprio(1);
      za = __builtin_amdgcn_mfma_f32_16x16x32_bf16(afa0, ba0, za, 0, 0, 0);
      zb = __builtin_amdgcn_mfma_f32_16x16x32_bf16(afb0, bb0, zb, 0, 0, 0);
      za = __builtin_amdgcn_mfma_f32_16x16x32_bf16(afa1, ba1, za, 0, 0, 0);
      zb = __builtin_amdgcn_mfma_f32_16x16x32_bf16(afb1, bb1, zb, 0, 0, 0);
      __builtin_amdgcn_s_setprio(0);
      acca[ct] = za; accb[ct] = zb;
    }
#pragma unroll
    for (int reg = 0; reg < 4; reg++) {
      if (rra[reg] >= 0) {
        f32x4 v = {acca[0][reg], acca[1][reg], acca[2][reg], acca[3][reg]};
        __builtin_nontemporal_store(v,
            (f32x4*)&out[((size_t)(bh * SS + rra[reg])) * SS + j0 + l16 * 4]);
      }
      if (rrb[reg] >= 0) {
        f32x4 v = {accb[0][reg], accb[1][reg], accb[2][reg], accb[3][reg]};
        __builtin_nontemporal_store(v,
            (f32x4*)&out[((size_t)(bh * SS + rrb[reg])) * SS + j0 + l16 * 4]);
      }
    }
  }
}

extern "C" void kernel_launch(void* const* d_in, const int* in_sizes, int n_in,
                              void* d_out, int out_size, void* d_ws, size_t ws_size,
                              hipStream_t stream) {
  const float* q = (const float*)d_in[0];
  const float* k = (const float*)d_in[1];
  const int* bseq = (const int*)d_in[2];
  const float* W1 = (const float*)d_in[3];
  const float* alpha = (const float*)d_in[4];
  float* out = (float*)d_out;
  char* ws = (char*)d_ws;
  unsigned short* W1mbf = (unsigned short*)(ws + WS_W1);
  int* ridx = (int*)(ws + WS_RIDX);
  int* gst = (int*)(ws + WS_GST);

  hipLaunchKernelGGL(k_prep, dim3(8 + NC * HH), dim3(256), 0, stream,
                     bseq, W1, alpha, ridx, gst, W1mbf);
  hipLaunchKernelGGL(k_fused, dim3(64 * (SS / CT)), dim3(768), 0, stream,
                     q, k, bseq, W1mbf, ridx, gst, out);
}